// Round 7
// baseline (187.884 us; speedup 1.0000x reference)
//
#include <hip/hip_runtime.h>

// DetectionLoss: B=32768, G=7, A=2, C=3, M=20.
// R9: MLP experiment. Four structures (R3/R6 monoliths, R7/R8 splits) all
// land at ~62-67us kernel time with VGPR_Count=36 and chip read rate ~1.7TB/s
// while HBM sits 85% idle (R6: FETCH 64MB, WRITE ~0, fill writes at 6.8TB/s).
// Model: stores need no return; LOADS are capped by bytes-in-flight, and every
// prior version had the same shallow ~2-3 loads/wave MLP. This round changes
// ONE variable: the noobj stream issues 8 independent lane-contiguous float4
// loads per thread (3136 blocks x 256thr x 8 chunks = n4 exactly; block covers
// a contiguous 32KB window), parity softplus, block reduce -> 1 float.
// Plain loads (no nt): L3 retention across iterations cut FETCH 103->64MB.
// assign (wave-per-batch, R8-verbatim) and reduce unchanged for clean A/B.

namespace {
constexpr int kG = 7;
constexpr int kA = 2;
constexpr int kM = 20;
constexpr int kCells = kG * kG * kA;     // 98
constexpr int kCh = 8;                   // 5 + C
constexpr int kWavesA = 8;               // waves per assign block (1 batch/wave)
constexpr int kBlockA = 64 * kWavesA;    // 512
constexpr int kBlockN = 256;             // noobj stream block
constexpr int kUnroll = 8;               // independent float4 loads per thread
constexpr int kChunksPerBlk = kBlockN * kUnroll;   // 2048 chunks = 32KB
}

typedef float f32x4 __attribute__((ext_vector_type(4)));

__device__ __forceinline__ float softplus_fast(float x) {
    // logaddexp(x,0); fast exp/log — absmax threshold leaves huge slack
    return fmaxf(x, 0.0f) + __logf(1.0f + __expf(-fabsf(x)));
}

// ---------------- Kernel A: wave-per-batch assignment + positives ----------------
__global__ __launch_bounds__(kBlockA) void det_loss_assign(
    const float* __restrict__ preds,
    const float4* __restrict__ tboxes4,
    const int* __restrict__ tlabels,
    const int* __restrict__ nobjs,
    const float* __restrict__ anchors,
    const float* __restrict__ cweights,
    float* __restrict__ partialA,  // SoA [5][NA]
    int B, int NA)
{
    __shared__ float s_red[kWavesA][5];

    const int tid  = threadIdx.x;
    const int wave = tid >> 6;
    const int m    = tid & 63;                     // lane; lanes 0..19 = targets
    const int wb   = blockIdx.x * kWavesA + wave;  // batch handled by this wave
    const bool active = (wb < B);

    const float a00 = anchors[0], a01 = anchors[1];
    const float a10 = anchors[2], a11 = anchors[3];

    // broadcast num_objs for this batch
    int nob = 0;
    if (active && m == 0) nob = nobjs[wb];
    nob = __shfl(nob, 0, 64);

    // ---- per-lane target assignment ----
    int cell = -1;                                 // batch-local cell in [0,98)
    float4 tv = make_float4(0.f, 0.f, 0.f, 0.f);
    if (active && m < kM) {
        const float4 box = tboxes4[(size_t)wb * kM + m];
        const float x1 = box.x, y1 = box.y, x2 = box.z, y2 = box.w;
        const float cx = (x1 + x2) * 0.5f, cy = (y1 + y2) * 0.5f;
        const float w = x2 - x1, h = y2 - y1;
        if (w > 0.f && h > 0.f && m < nob) {
            const int gi = min(max((int)floorf(cy * (float)kG), 0), kG - 1);
            const int gj = min(max((int)floorf(cx * (float)kG), 0), kG - 1);
            const float wg = w * (float)kG, hg = h * (float)kG;
            const float i0 = fminf(wg, a00) * fminf(hg, a01);
            const float u0 = wg * hg + a00 * a01 - i0;
            const float r0 = i0 / (u0 + 1e-6f);
            const float i1 = fminf(wg, a10) * fminf(hg, a11);
            const float u1 = wg * hg + a10 * a11 - i1;
            const float r1 = i1 / (u1 + 1e-6f);
            const int a = (r1 > r0) ? 1 : 0;       // argmax, first-max wins
            const float aw = a ? a10 : a00;
            const float ah = a ? a11 : a01;
            tv.x = cx * (float)kG - (float)gj;
            tv.y = cy * (float)kG - (float)gi;
            tv.z = __logf(fmaxf(wg, 0.01f) / (aw + 1e-6f));
            tv.w = __logf(fmaxf(hg, 0.01f) / (ah + 1e-6f));
            cell = (gi * kG + gj) * kA + a;
        }
    }

    // ---- dedup: last-write-wins == lose if ANY later lane has same cell ----
    bool win = (cell >= 0);
    #pragma unroll
    for (int s = 1; s < kM; ++s) {
        const int other = __shfl_down(cell, s, 64);
        if ((m + s < kM) && (cell >= 0) && (other == cell)) win = false;
    }
    const unsigned long long bal = __ballot(win);   // num_pos = popcount

    // ---- winner lanes: gather 32B preds cell + label, compute terms ----
    float accO = 0.f, accN = 0.f, accB = 0.f, accC = 0.f;
    if (win) {
        const float4* pc = (const float4*)(preds + ((size_t)wb * kCells + cell) * kCh);
        const float4 p0 = pc[0];
        const float4 p1 = pc[1];
        const float spp = softplus_fast(p0.x);
        accN -= spp;            // remove noobj term the stream kernel adds
        accO += spp - p0.x;     // softplus(-x) == softplus(x) - x
        float d, ad;
        d = p0.y - tv.x; ad = fabsf(d); accB += (ad < 1.f) ? 0.5f * d * d : ad - 0.5f;
        d = p0.z - tv.y; ad = fabsf(d); accB += (ad < 1.f) ? 0.5f * d * d : ad - 0.5f;
        d = p0.w - tv.z; ad = fabsf(d); accB += (ad < 1.f) ? 0.5f * d * d : ad - 0.5f;
        d = p1.x - tv.w; ad = fabsf(d); accB += (ad < 1.f) ? 0.5f * d * d : ad - 0.5f;
        const int lab = tlabels[(size_t)wb * kM + m];
        const float c0 = p1.y, c1 = p1.z, c2 = p1.w;
        const float mx = fmaxf(c0, fmaxf(c1, c2));
        const float lse = mx + __logf(__expf(c0 - mx) + __expf(c1 - mx) + __expf(c2 - mx));
        const float logit = (lab == 0) ? c0 : ((lab == 1) ? c1 : c2);
        accC += cweights[lab] * (lse - logit);
    }

    // ---- wave reduce (4 sums) ----
    float vals[4] = {accO, accN, accB, accC};
    #pragma unroll
    for (int k = 0; k < 4; ++k) {
        float v = vals[k];
        #pragma unroll
        for (int off = 32; off > 0; off >>= 1) v += __shfl_down(v, off, 64);
        vals[k] = v;
    }
    if (m == 0) {
        #pragma unroll
        for (int k = 0; k < 4; ++k) s_red[wave][k] = vals[k];
        s_red[wave][4] = (float)__popcll(bal);
    }
    __syncthreads();

    // ---- block combine + plain SoA stores ----
    if (tid == 0) {
        float t[5];
        #pragma unroll
        for (int k = 0; k < 5; ++k) {
            float s = 0.f;
            #pragma unroll
            for (int w = 0; w < kWavesA; ++w) s += s_red[w][k];
            t[k] = s;
        }
        #pragma unroll
        for (int k = 0; k < 5; ++k)
            partialA[(size_t)k * NA + blockIdx.x] = t[k];
    }
}

// ---------------- Kernel B: deep-MLP noobj stream ----------------
// Block b covers contiguous chunks [b*2048, (b+1)*2048): 8 lane-contiguous
// float4 loads per thread, all independent -> 8KB in flight per wave.
__global__ __launch_bounds__(kBlockN) void det_loss_noobj(
    const f32x4* __restrict__ preds4,
    float* __restrict__ partialN,  // [gridDim.x]
    long long n4)
{
    __shared__ float s_red[kBlockN / 64];
    const int tid = threadIdx.x;
    const long long base = (long long)blockIdx.x * kChunksPerBlk + tid;

    f32x4 v[kUnroll];
    #pragma unroll
    for (int k = 0; k < kUnroll; ++k) {
        const long long i = base + (long long)k * kBlockN;
        v[k] = (i < n4) ? preds4[i] : (f32x4){0.f, 0.f, 0.f, 0.f};
    }

    // chunk parity == tid parity (2048 and 256 both even): even tid holds obj
    float acc = 0.f;
    if ((tid & 1) == 0) {
        #pragma unroll
        for (int k = 0; k < kUnroll; ++k) {
            const long long i = base + (long long)k * kBlockN;
            if (i < n4) acc += softplus_fast(v[k].x);
        }
    }

    #pragma unroll
    for (int off = 32; off > 0; off >>= 1) acc += __shfl_down(acc, off, 64);
    if ((tid & 63) == 0) s_red[tid >> 6] = acc;
    __syncthreads();
    if (tid == 0) {
        float t = 0.f;
        #pragma unroll
        for (int w = 0; w < kBlockN / 64; ++w) t += s_red[w];
        partialN[blockIdx.x] = t;
    }
}

// ---------------- Reduce ----------------
__global__ __launch_bounds__(256) void det_loss_reduce(
    const float* __restrict__ partialA, int NA,
    const float* __restrict__ partialN, int NN,
    float* __restrict__ out)
{
    __shared__ float s_red[4][5];
    const int tid = threadIdx.x;
    float v[5] = {0.f, 0.f, 0.f, 0.f, 0.f};
    for (int i = tid; i < NA; i += 256) {
        #pragma unroll
        for (int k = 0; k < 5; ++k) v[k] += partialA[(size_t)k * NA + i];
    }
    for (int i = tid; i < NN; i += 256) v[1] += partialN[i];
    #pragma unroll
    for (int k = 0; k < 5; ++k) {
        float x = v[k];
        #pragma unroll
        for (int off = 32; off > 0; off >>= 1) x += __shfl_down(x, off, 64);
        v[k] = x;
    }
    const int wave = tid >> 6;
    const int lane = tid & 63;
    if (lane == 0) {
        #pragma unroll
        for (int k = 0; k < 5; ++k) s_red[wave][k] = v[k];
    }
    __syncthreads();
    if (tid == 0) {
        float t[5];
        #pragma unroll
        for (int k = 0; k < 5; ++k) {
            float s = 0.f;
            #pragma unroll
            for (int w = 0; w < 4; ++w) s += s_red[w][k];
            t[k] = s;
        }
        const float npv = fmaxf(t[4], 1.0f);
        out[0] = (5.0f * t[2] + 1.0f * t[0] + 0.5f * t[1] + 2.0f * t[3]) / npv;
    }
}

extern "C" void kernel_launch(void* const* d_in, const int* in_sizes, int n_in,
                              void* d_out, int out_size, void* d_ws, size_t ws_size,
                              hipStream_t stream) {
    const float* preds    = (const float*)d_in[0];
    const float* tboxes   = (const float*)d_in[1];
    const int*   tlabels  = (const int*)d_in[2];
    const int*   nobjs    = (const int*)d_in[3];
    const float* anchors  = (const float*)d_in[4];
    const float* cweights = (const float*)d_in[5];
    float* out = (float*)d_out;

    const int B = in_sizes[0] / (kCells * kCh);   // /784
    const int blocksA = (B + kWavesA - 1) / kWavesA;              // 4096
    const long long n4 = (long long)B * kCells * 2;               // 6,422,528
    const int blocksN = (int)((n4 + kChunksPerBlk - 1) / kChunksPerBlk);  // 3136

    float* partialA = (float*)d_ws;                    // [5][blocksA]
    float* partialN = partialA + (size_t)5 * blocksA;  // [blocksN]

    det_loss_assign<<<blocksA, kBlockA, 0, stream>>>(
        preds, (const float4*)tboxes, tlabels, nobjs, anchors, cweights,
        partialA, B, blocksA);
    det_loss_noobj<<<blocksN, kBlockN, 0, stream>>>(
        (const f32x4*)preds, partialN, n4);
    det_loss_reduce<<<1, 256, 0, stream>>>(partialA, blocksA, partialN, blocksN, out);
}